// Round 3
// baseline (841.678 us; speedup 1.0000x reference)
//
#include <hip/hip_runtime.h>
#include <math.h>

#define N_NODES 50000
#define N_EDGES 1600000
#define HIDDEN  128
#define DC      16      // number of RBF centers
#define EPB     128     // edges per tile
#define BLOCK   256
#define TILES   5       // tiles per block (persistent): 2500 * 5 * 128 = 1.6M exact
#define GRID    2500
#define RBF_LD  20      // padded leading dim: 80 B rows, keeps 16B alignment

// mu_k = k * 6/15 = k * 0.4   (linspace(0,6,16) is endpoint-inclusive!)
// sigma = (6-0)/16 = 0.375 -> inv_sigma = 8/3
#define MU_STEP   0.4f
#define INV_SIGMA 2.6666666666666665f

typedef float f32x2 __attribute__((ext_vector_type(2)));
typedef float f32x4 __attribute__((ext_vector_type(4)));
// pos rows are 12 B so float4 endpoint loads are only 4B-aligned; declare that.
typedef f32x4 f32x4u __attribute__((aligned(4)));

__device__ __forceinline__ float fast_sigmoid(float x) {
    float e = __expf(-x);                       // v_mul + v_exp_f32
    return __builtin_amdgcn_rcpf(1.0f + e);     // v_rcp_f32 (~1 ulp, fine at tol)
}

__device__ __forceinline__ f32x2 fma2v(float s, f32x2 w, f32x2 a) {
    f32x2 sv = s;                               // splat; foldable into op_sel
    return __builtin_elementwise_fma(sv, w, a); // candidate v_pk_fma_f32
}

__global__ __launch_bounds__(BLOCK, 6) void edge_attr_kernel(
    const float* __restrict__ pos,        // [N_NODES, 3]
    const int* __restrict__ ei,           // [2, N_EDGES] (harness delivers int32)
    const float* __restrict__ W,          // [DC, HIDDEN]
    const float* __restrict__ b,          // [HIDDEN]
    float* __restrict__ out)              // [N_EDGES, HIDDEN]
{
    // double-buffered rbf tile: phase-2 of tile t overlaps gather+exp of t+1
    __shared__ float rbf_s[2][EPB][RBF_LD];

    const int tid = threadIdx.x;
    const int h2  = tid & 63;   // which float2 chunk of the 128 hidden cols
    const int wv  = tid >> 6;   // wave id 0..3
    const int el  = tid & 127;  // edge within tile (2 threads per edge)
    const int kg  = tid >> 7;   // 0/1 -> this thread's 8 RBF centers

    const long eb = (long)blockIdx.x * (TILES * EPB);

    // ---- W columns into registers (contiguous 512B/instr, L2-hot)
    f32x2 wcol[DC];
    #pragma unroll
    for (int k = 0; k < DC; ++k)
        wcol[k] = *reinterpret_cast<const f32x2*>(W + k * HIDDEN + h2 * 2);
    const f32x2 bias = *reinterpret_cast<const f32x2*>(b + h2 * 2);

    // ---- prologue: tile 0 dist + RBF (fused, single pass)
    {
        const long e = eb + el;
        const int s = ei[e];
        const int d = ei[N_EDGES + e];
        const f32x4 ps = *reinterpret_cast<const f32x4u*>(pos + 3 * s);
        const f32x4 pd = *reinterpret_cast<const f32x4u*>(pos + 3 * d);
        const float dx = ps.x - pd.x, dy = ps.y - pd.y, dz = ps.z - pd.z;
        const float dist = sqrtf(dx * dx + dy * dy + dz * dz);
        f32x4 r0, r1;
        #pragma unroll
        for (int j = 0; j < 4; ++j) {
            const float t0 = (dist - MU_STEP * (float)(kg * 8 + j)) * INV_SIGMA;
            const float t1 = (dist - MU_STEP * (float)(kg * 8 + 4 + j)) * INV_SIGMA;
            r0[j] = __expf(-t0 * t0);
            r1[j] = __expf(-t1 * t1);
        }
        *reinterpret_cast<f32x4*>(&rbf_s[0][el][kg * 8 + 0]) = r0;
        *reinterpret_cast<f32x4*>(&rbf_s[0][el][kg * 8 + 4]) = r1;
    }
    __syncthreads();

    #pragma unroll 1   // keep code small; cur/addresses are cheap runtime math
    for (int t = 0; t < TILES; ++t) {
        const int cur = t & 1;

        // ---- issue tile t+1 gathers BEFORE the compute burst (use much later)
        f32x4 psn = {}, pdn = {};
        if (t + 1 < TILES) {
            const long e = eb + (long)(t + 1) * EPB + el;
            const int sn = ei[e];
            const int dn = ei[N_EDGES + e];
            psn = *reinterpret_cast<const f32x4u*>(pos + 3 * sn);
            pdn = *reinterpret_cast<const f32x4u*>(pos + 3 * dn);
        }

        // ---- phase 2: out[e][h] = sigmoid(sum_k rbf[k] * W[k][h] + b[h])
        const long row0 = eb + (long)t * EPB;
        float* op = out + (row0 + wv) * HIDDEN + h2 * 2;
        #pragma unroll 4
        for (int i = 0; i < EPB / 4; ++i) {
            const int erow = wv + i * 4;

            // 4x ds_read_b128, same address across the wave = broadcast (free)
            const f32x4* rp = reinterpret_cast<const f32x4*>(&rbf_s[cur][erow][0]);
            const f32x4 ra = rp[0];
            const f32x4 rb = rp[1];
            const f32x4 rc = rp[2];
            const f32x4 rd = rp[3];

            f32x2 acc = bias;
            acc = fma2v(ra.x, wcol[0],  acc);
            acc = fma2v(ra.y, wcol[1],  acc);
            acc = fma2v(ra.z, wcol[2],  acc);
            acc = fma2v(ra.w, wcol[3],  acc);
            acc = fma2v(rb.x, wcol[4],  acc);
            acc = fma2v(rb.y, wcol[5],  acc);
            acc = fma2v(rb.z, wcol[6],  acc);
            acc = fma2v(rb.w, wcol[7],  acc);
            acc = fma2v(rc.x, wcol[8],  acc);
            acc = fma2v(rc.y, wcol[9],  acc);
            acc = fma2v(rc.z, wcol[10], acc);
            acc = fma2v(rc.w, wcol[11], acc);
            acc = fma2v(rd.x, wcol[12], acc);
            acc = fma2v(rd.y, wcol[13], acc);
            acc = fma2v(rd.z, wcol[14], acc);
            acc = fma2v(rd.w, wcol[15], acc);

            f32x2 res;
            res.x = fast_sigmoid(acc.x);
            res.y = fast_sigmoid(acc.y);

            *reinterpret_cast<f32x2*>(op) = res;   // 512B/wave-instr, full lines
            op += 4 * HIDDEN;
        }

        // ---- finish tile t+1: dist + RBF into the other buffer
        if (t + 1 < TILES) {
            const float dx = psn.x - pdn.x, dy = psn.y - pdn.y, dz = psn.z - pdn.z;
            const float dist = sqrtf(dx * dx + dy * dy + dz * dz);
            f32x4 r0, r1;
            #pragma unroll
            for (int j = 0; j < 4; ++j) {
                const float t0 = (dist - MU_STEP * (float)(kg * 8 + j)) * INV_SIGMA;
                const float t1 = (dist - MU_STEP * (float)(kg * 8 + 4 + j)) * INV_SIGMA;
                r0[j] = __expf(-t0 * t0);
                r1[j] = __expf(-t1 * t1);
            }
            *reinterpret_cast<f32x4*>(&rbf_s[cur ^ 1][el][kg * 8 + 0]) = r0;
            *reinterpret_cast<f32x4*>(&rbf_s[cur ^ 1][el][kg * 8 + 4]) = r1;
        }

        // single barrier per tile: protects rbf_s[cur^1] writes (for t+1 reads)
        // and rbf_s[cur] reads (overwritten in t+1's tail)
        __syncthreads();
    }
}

extern "C" void kernel_launch(void* const* d_in, const int* in_sizes, int n_in,
                              void* d_out, int out_size, void* d_ws, size_t ws_size,
                              hipStream_t stream) {
    const float* pos = (const float*)d_in[0];
    const int*   ei  = (const int*)d_in[1];     // harness delivers integers as int32
    const float* W   = (const float*)d_in[2];
    const float* b   = (const float*)d_in[3];
    float*       out = (float*)d_out;

    dim3 grid(GRID);   // 2500 blocks x 5 tiles x 128 edges = 1,600,000 exactly
    edge_attr_kernel<<<grid, BLOCK, 0, stream>>>(pos, ei, W, b, out);
}